// Round 5
// baseline (356.931 us; speedup 1.0000x reference)
//
#include <hip/hip_runtime.h>

#define N_NODES 4194304
#define LEVELS  10
#define COARSE  8192
#define NNZ_E   8388608
#define NCHUNK  16384    // N_NODES / 256
#define NB      256      // row and col bucket count
#define CB_SZ   16384    // cols per col-bucket (64 KiB fp32 LDS slice)
#define RB_SZ   16384    // rows per row-bucket (64 KiB LDS accumulator)
#define HB      2048     // histogram/binning blocks
#define EPB     4096     // edges per binning block
#define KMAX    34       // register entries per thread in D4 (34*1024 > max bucket)

typedef int          v4i __attribute__((ext_vector_type(4)));
typedef float        v4f __attribute__((ext_vector_type(4)));
typedef unsigned int v4u __attribute__((ext_vector_type(4)));

static __device__ __forceinline__ unsigned short f2bf(float x) {
    unsigned u = __float_as_uint(x);
    return (unsigned short)((u + 0x7FFFu + ((u >> 16) & 1u)) >> 16);
}
static __device__ __forceinline__ float bf2f(unsigned short h) {
    return __uint_as_float((unsigned)h << 16);
}
static __device__ __forceinline__ unsigned f18(float p) {   // 1s+8e+9m, RN
    return ((__float_as_uint(p) + 0x2000u) >> 14) & 0x3FFFFu;
}

// ================= D1: HODLR moments (blocks 0..4095) + dual hist (4096..6143)
__global__ __launch_bounds__(256) void kD1(const float* __restrict__ z,
                                           float2* __restrict__ M,
                                           float* __restrict__ S,
                                           float* __restrict__ out,
                                           const int* __restrict__ rows,
                                           const int* __restrict__ cols,
                                           unsigned* __restrict__ colBO,
                                           unsigned* __restrict__ rowBC) {
    int b = blockIdx.x, t = threadIdx.x;
    if (b < 4096) {
        if (b == 0) {
            for (int i = t; i < 2046 * 2; i += 256) S[i] = 0.f;
            if (t == 0) out[0] = 0.f;
        }
        int lane = t & 63, wave = t >> 6;
        int chunk = b * 4 + wave;
        int base = chunk * 256 + lane * 4;
        float4 zv = *(const float4*)(z + base);
        float a0 = 0.f, a1 = 0.f;
        const float* zp = (const float*)&zv;
#pragma unroll
        for (int j = 0; j < 4; ++j) {
            float p = ((float)(base + j) + 0.5f) * (1.0f / 512.0f) - 0.5f;
            p = fminf(fmaxf(p, 0.0f), (float)(COARSE - 1));
            float f = p - floorf(p);
            a0 += zp[j] * (1.0f - f);
            a1 += zp[j] * f;
        }
#pragma unroll
        for (int off = 32; off >= 1; off >>= 1) {
            a0 += __shfl_xor(a0, off, 64);
            a1 += __shfl_xor(a1, off, 64);
        }
        if (lane == 0) M[chunk] = make_float2(a0, a1);
    } else {
        __shared__ unsigned hc[NB], hr[NB];
        int blk = b - 4096;
        hc[t] = 0u; hr[t] = 0u;
        __syncthreads();
        int base = blk * EPB;
#pragma unroll
        for (int it = 0; it < 4; ++it) {
            int e = base + it * 1024 + t * 4;
            v4i r = *(const v4i*)(rows + e);
            v4i c = *(const v4i*)(cols + e);
            atomicAdd(&hr[r.x >> 14], 1u); atomicAdd(&hr[r.y >> 14], 1u);
            atomicAdd(&hr[r.z >> 14], 1u); atomicAdd(&hr[r.w >> 14], 1u);
            atomicAdd(&hc[c.x >> 14], 1u); atomicAdd(&hc[c.y >> 14], 1u);
            atomicAdd(&hc[c.z >> 14], 1u); atomicAdd(&hc[c.w >> 14], 1u);
        }
        __syncthreads();
        colBO[t * HB + blk] = hc[t];
        rowBC[t * HB + blk] = hr[t];
    }
}

// ================= D2: kB level sums (0..79) + col scan (80..335) + row sums (336..591)
__global__ __launch_bounds__(1024) void kD2(const float2* __restrict__ M,
                                            const float* __restrict__ V,
                                            float* __restrict__ S,
                                            unsigned* __restrict__ colBO,
                                            unsigned* __restrict__ colTotal,
                                            const unsigned* __restrict__ rowBC,
                                            unsigned* __restrict__ rowTotal) {
    int b = blockIdx.x, t = threadIdx.x;
    if (b < 80) {
        int lvl = b >> 3, slice = b & 7;
        const float2* Vl = (const float2*)(V + lvl * COARSE * 2);
        float s0 = 0.f, s1 = 0.f;
        int c0 = slice * 2048 + t * 2;
#pragma unroll
        for (int cc = 0; cc < 2; ++cc) {
            int c = c0 + cc;
            float2 m = M[c];
            int k = (c > 0) ? ((c - 1) >> 1) : 0;
            int kp = min(k + 1, COARSE - 1);
            float2 vk = Vl[k], vkp = Vl[kp];
            s0 += vk.x * m.x + vkp.x * m.y;
            s1 += vk.y * m.x + vkp.y * m.y;
        }
        int gw = min(1 << (12 - lvl), 64);
        for (int sh = gw >> 1; sh >= 1; sh >>= 1) {
            s0 += __shfl_xor(s0, sh, 64);
            s1 += __shfl_xor(s1, sh, 64);
        }
        if ((t & (gw - 1)) == 0) {
            int bb = c0 >> (13 - lvl);
            int soff = (2 << lvl) - 2;
            unsafeAtomicAdd(&S[(soff + bb) * 2 + 0], s0);
            unsafeAtomicAdd(&S[(soff + bb) * 2 + 1], s1);
        }
    } else if (b < 336) {
        int bb = b - 80;
        __shared__ unsigned wsum[4], wbase[4];
        if (t < 256) {
            unsigned* p = colBO + bb * HB;
            v4u a = *(const v4u*)(p + t * 8);
            v4u c = *(const v4u*)(p + t * 8 + 4);
            unsigned s = a.x + a.y + a.z + a.w + c.x + c.y + c.z + c.w;
            unsigned incl = s;
#pragma unroll
            for (int off = 1; off < 64; off <<= 1) {
                unsigned n = __shfl_up(incl, off, 64);
                if ((t & 63) >= off) incl += n;
            }
            if ((t & 63) == 63) wsum[t >> 6] = incl;
            __syncthreads();
            if (t == 0) {
                unsigned acc = 0;
                for (int i = 0; i < 4; ++i) { wbase[i] = acc; acc += wsum[i]; }
                colTotal[bb] = acc;
            }
            __syncthreads();
            unsigned excl = wbase[t >> 6] + incl - s;
            v4u e0, e1;
            e0.x = excl;       e0.y = e0.x + a.x; e0.z = e0.y + a.y; e0.w = e0.z + a.z;
            e1.x = e0.w + a.w; e1.y = e1.x + c.x; e1.z = e1.y + c.y; e1.w = e1.z + c.z;
            *(v4u*)(p + t * 8) = e0;
            *(v4u*)(p + t * 8 + 4) = e1;
        } else {
            __syncthreads();
            __syncthreads();
        }
    } else {
        int bb = b - 336;
        __shared__ unsigned red[8];
        unsigned s = 0;
        if (t < 512) {
            v4u vv = *(const v4u*)(rowBC + bb * HB + t * 4);
            s = vv.x + vv.y + vv.z + vv.w;
        }
#pragma unroll
        for (int off = 32; off >= 1; off >>= 1) s += __shfl_xor(s, off, 64);
        if (t < 512 && (t & 63) == 0) red[t >> 6] = s;
        __syncthreads();
        if (t == 0) {
            unsigned tot = 0;
            for (int i = 0; i < 8; ++i) tot += red[i];
            rowTotal[bb] = tot;
        }
    }
}

// ================= D3: w=diag*z+lowrank (0..4095) + col-binning (4096..6143) + row scan (6144)
__global__ __launch_bounds__(256) void kD3(const float* __restrict__ diag,
                                           const float* __restrict__ z,
                                           const float* __restrict__ S,
                                           const float* __restrict__ U,
                                           float* __restrict__ w,
                                           const int* __restrict__ rows,
                                           const int* __restrict__ cols,
                                           const float* __restrict__ vals,
                                           const unsigned* __restrict__ colTotal,
                                           const unsigned* __restrict__ colBO,
                                           uint2* __restrict__ colBinned,
                                           const unsigned* __restrict__ rowTotal,
                                           unsigned* __restrict__ rowBase,
                                           unsigned* __restrict__ rowCtr) {
    int b = blockIdx.x, t = threadIdx.x;
    if (b < 4096) {
        int tid = b * 256 + t;
        int base = tid * 4;
        int c = base >> 8;
        int k = (c > 0) ? ((c - 1) >> 1) : 0;
        int kp = min(k + 1, COARSE - 1);
        float g0 = 0.f, g1 = 0.f;
#pragma unroll
        for (int lvl = 0; lvl < LEVELS; ++lvl) {
            int sib = (c >> (13 - lvl)) ^ 1;
            int soff = (2 << lvl) - 2;
            float2 s2 = ((const float2*)S)[soff + sib];
            const float2* Ul = (const float2*)(U + lvl * COARSE * 2);
            float2 uk = Ul[k], ukp = Ul[kp];
            g0 += uk.x * s2.x + uk.y * s2.y;
            g1 += ukp.x * s2.x + ukp.y * s2.y;
        }
        float4 d4 = *(const float4*)(diag + base);
        float4 z4 = *(const float4*)(z + base);
        const float* dp = (const float*)&d4;
        const float* zp = (const float*)&z4;
        float4 w4;
        float* wp = (float*)&w4;
#pragma unroll
        for (int j = 0; j < 4; ++j) {
            float p = ((float)(base + j) + 0.5f) * (1.0f / 512.0f) - 0.5f;
            p = fminf(fmaxf(p, 0.0f), (float)(COARSE - 1));
            float f = p - floorf(p);
            wp[j] = dp[j] * zp[j] + (g0 + f * (g1 - g0));
        }
        *(float4*)(w + base) = w4;
    } else if (b < 6144) {
        int blk = b - 4096;
        __shared__ unsigned ctr[NB];
        __shared__ unsigned wsum[4], wbase[4];
        unsigned tv = colTotal[t];
        unsigned incl = tv;
#pragma unroll
        for (int off = 1; off < 64; off <<= 1) {
            unsigned n = __shfl_up(incl, off, 64);
            if ((t & 63) >= off) incl += n;
        }
        if ((t & 63) == 63) wsum[t >> 6] = incl;
        __syncthreads();
        if (t == 0) {
            unsigned a = 0;
            for (int i = 0; i < 4; ++i) { wbase[i] = a; a += wsum[i]; }
        }
        __syncthreads();
        ctr[t] = (wbase[t >> 6] + incl - tv) + colBO[t * HB + blk];
        __syncthreads();
        int base = blk * EPB;
        v4i r[4], c[4];
        v4f v[4];
#pragma unroll
        for (int j = 0; j < 4; ++j) {
            int e = base + j * 1024 + t * 4;
            r[j] = *(const v4i*)(rows + e);
            c[j] = *(const v4i*)(cols + e);
            v[j] = *(const v4f*)(vals + e);
        }
#pragma unroll
        for (int j = 0; j < 4; ++j) {
            const int* rp = (const int*)&r[j];
            const int* cp = (const int*)&c[j];
            const float* vp = (const float*)&v[j];
#pragma unroll
            for (int kk = 0; kk < 4; ++kk) {
                int row = rp[kk], col = cp[kk];
                int cb = col >> 14;
                int cl = col & 16383;
                unsigned key = (unsigned)row | ((unsigned)(cl & 0x3FF) << 22);
                unsigned aux = (unsigned)(cl >> 10) | ((unsigned)f2bf(vp[kk]) << 16);
                unsigned pos = atomicAdd(&ctr[cb], 1u);
                colBinned[pos] = make_uint2(key, aux);
            }
        }
    } else {
        __shared__ unsigned wsum[4], wbase[4];
        unsigned tv = rowTotal[t];
        unsigned incl = tv;
#pragma unroll
        for (int off = 1; off < 64; off <<= 1) {
            unsigned n = __shfl_up(incl, off, 64);
            if ((t & 63) >= off) incl += n;
        }
        if ((t & 63) == 63) wsum[t >> 6] = incl;
        __syncthreads();
        if (t == 0) {
            unsigned a = 0;
            for (int i = 0; i < 4; ++i) { wbase[i] = a; a += wsum[i]; }
        }
        __syncthreads();
        unsigned excl = wbase[t >> 6] + incl - tv;
        rowBase[t] = excl;
        rowCtr[t] = excl;
        if (t == 255) rowBase[256] = excl + tv;
    }
}

// ================= D4: per col-bucket — LDS w slice, products, row-bucket scatter
__global__ __launch_bounds__(1024) void kD4(const unsigned* __restrict__ colTotal,
                                            const uint2* __restrict__ colBinned,
                                            const float* __restrict__ w,
                                            unsigned* __restrict__ rowCtr,
                                            unsigned* __restrict__ packed) {
    __shared__ float wSl[CB_SZ];          // 64 KiB
    __shared__ unsigned rh[NB], ctr2[NB];
    __shared__ unsigned wsum[4], wbase[4];
    __shared__ unsigned sS, sN;
    int b = blockIdx.x, t = threadIdx.x;
    unsigned tv = 0, incl = 0;
    if (t < 256) {
        rh[t] = 0u;
        tv = colTotal[t];
        incl = tv;
#pragma unroll
        for (int off = 1; off < 64; off <<= 1) {
            unsigned n = __shfl_up(incl, off, 64);
            if ((t & 63) >= off) incl += n;
        }
        if ((t & 63) == 63) wsum[t >> 6] = incl;
    }
    __syncthreads();
    if (t == 0) {
        unsigned a = 0;
        for (int i = 0; i < 4; ++i) { wbase[i] = a; a += wsum[i]; }
    }
    __syncthreads();
    if (t < 256 && t == b) { sS = wbase[t >> 6] + incl - tv; sN = tv; }
    __syncthreads();
    // load w slice into LDS
    const float4* wg = (const float4*)(w + (size_t)b * CB_SZ);
    for (int i = t; i < CB_SZ / 4; i += 1024) ((float4*)wSl)[i] = wg[i];
    unsigned s0 = sS, n = sN;
    // load entries to registers
    uint2 ev[KMAX];
#pragma unroll
    for (int k = 0; k < KMAX; ++k) {
        unsigned i = (unsigned)(k * 1024 + t);
        if (i < n) ev[k] = colBinned[s0 + i];
    }
    // row-bucket histogram
#pragma unroll
    for (int k = 0; k < KMAX; ++k) {
        if ((unsigned)(k * 1024 + t) < n)
            atomicAdd(&rh[(ev[k].x & 0x3FFFFFu) >> 14], 1u);
    }
    for (unsigned i = KMAX * 1024 + t; i < n; i += 1024) {
        uint2 e = colBinned[s0 + i];
        atomicAdd(&rh[(e.x & 0x3FFFFFu) >> 14], 1u);
    }
    __syncthreads();
    if (t < 256) ctr2[t] = atomicAdd(&rowCtr[t], rh[t]);
    __syncthreads();
    // compute products and scatter into row buckets
#pragma unroll
    for (int k = 0; k < KMAX; ++k) {
        if ((unsigned)(k * 1024 + t) < n) {
            uint2 e = ev[k];
            unsigned cl = (e.x >> 22) | ((e.y & 0xFu) << 10);
            float p = bf2f((unsigned short)(e.y >> 16)) * wSl[cl];
            unsigned rb = (e.x & 0x3FFFFFu) >> 14;
            unsigned pos = atomicAdd(&ctr2[rb], 1u);
            packed[pos] = ((e.x & 0x3FFFu) << 18) | f18(p);
        }
    }
    for (unsigned i = KMAX * 1024 + t; i < n; i += 1024) {
        uint2 e = colBinned[s0 + i];
        unsigned cl = (e.x >> 22) | ((e.y & 0xFu) << 10);
        float p = bf2f((unsigned short)(e.y >> 16)) * wSl[cl];
        unsigned rb = (e.x & 0x3FFFFFu) >> 14;
        unsigned pos = atomicAdd(&ctr2[rb], 1u);
        packed[pos] = ((e.x & 0x3FFFu) << 18) | f18(p);
    }
}

// ================= D5: per row-bucket LDS accumulate + fused loss
__global__ __launch_bounds__(1024) void kD5(const unsigned* __restrict__ packed,
                                            const unsigned* __restrict__ rowBase,
                                            const float* __restrict__ z,
                                            float* __restrict__ out) {
    __shared__ float acc[RB_SZ];          // 64 KiB
    __shared__ float red[16];
    int b = blockIdx.x, t = threadIdx.x;
    unsigned s0 = rowBase[b], n = rowBase[b + 1] - s0;
    for (int i = t; i < RB_SZ / 4; i += 1024) ((float4*)acc)[i] = make_float4(0.f, 0.f, 0.f, 0.f);
    __syncthreads();
    for (unsigned i = t; i < n; i += 1024) {
        unsigned e = packed[s0 + i];
        atomicAdd(&acc[e >> 18], __uint_as_float((e & 0x3FFFFu) << 14));
    }
    __syncthreads();
    float part = 0.f;
    int gbase = b * RB_SZ;
    for (int i = t; i < RB_SZ; i += 1024) {
        float d = acc[i] - z[gbase + i];
        part += d * d;
    }
#pragma unroll
    for (int off = 32; off >= 1; off >>= 1) part += __shfl_xor(part, off, 64);
    if ((t & 63) == 0) red[t >> 6] = part;
    __syncthreads();
    if (t == 0) {
        float s = 0.f;
        for (int i = 0; i < 16; ++i) s += red[i];
        unsafeAtomicAdd(out, s * (1.0f / (float)N_NODES));
    }
}

extern "C" void kernel_launch(void* const* d_in, const int* in_sizes, int n_in,
                              void* d_out, int out_size, void* d_ws, size_t ws_size,
                              hipStream_t stream) {
    const float* diag  = (const float*)d_in[0];
    const float* U     = (const float*)d_in[1];
    const float* V     = (const float*)d_in[2];
    const float* Avals = (const float*)d_in[3];
    const float* z     = (const float*)d_in[4];
    const int*   Aidx  = (const int*)d_in[5];
    const int* rows = Aidx;
    const int* cols = Aidx + NNZ_E;

    char* ws = (char*)d_ws;
    size_t off = 0;
    float* w           = (float*)(ws + off);        off += (size_t)N_NODES * 4;     // 16 MiB
    uint2* colBinned   = (uint2*)(ws + off);        off += (size_t)NNZ_E * 8;       // 64 MiB
    unsigned* packed   = (unsigned*)(ws + off);     off += (size_t)NNZ_E * 4;       // 32 MiB
    unsigned* colBO    = (unsigned*)(ws + off);     off += (size_t)NB * HB * 4;     // 2 MiB
    unsigned* rowBC    = (unsigned*)(ws + off);     off += (size_t)NB * HB * 4;     // 2 MiB
    float2* M          = (float2*)(ws + off);       off += (size_t)NCHUNK * 8;      // 128 KiB
    float* S           = (float*)(ws + off);        off += 16384;
    unsigned* colTotal = (unsigned*)(ws + off);     off += 1024;
    unsigned* rowTotal = (unsigned*)(ws + off);     off += 1024;
    unsigned* rowCtr   = (unsigned*)(ws + off);     off += 1024;
    unsigned* rowBase  = (unsigned*)(ws + off);     off += 1040;

    kD1<<<6144, 256, 0, stream>>>(z, M, S, (float*)d_out, rows, cols, colBO, rowBC);
    kD2<<<592, 1024, 0, stream>>>(M, V, S, colBO, colTotal, rowBC, rowTotal);
    kD3<<<6145, 256, 0, stream>>>(diag, z, S, U, w, rows, cols, Avals,
                                  colTotal, colBO, colBinned, rowTotal, rowBase, rowCtr);
    kD4<<<256, 1024, 0, stream>>>(colTotal, colBinned, w, rowCtr, packed);
    kD5<<<256, 1024, 0, stream>>>(packed, rowBase, z, (float*)d_out);
}

// Round 6
// 328.000 us; speedup vs baseline: 1.0882x; 1.0882x over previous
//
#include <hip/hip_runtime.h>

#define N_NODES 4194304
#define LEVELS  10
#define COARSE  8192
#define NNZ_E   8388608
#define NCHUNK  16384    // N_NODES / 256
#define NB      256      // row buckets
#define BROWS   16384    // rows per bucket (64 KiB LDS accumulator)
#define BSH     14       // row >> BSH = bucket
#define HB      2048     // histogram/scatter blocks
#define EPB     4096     // edges per block

typedef int          v4i __attribute__((ext_vector_type(4)));
typedef float        v4f __attribute__((ext_vector_type(4)));
typedef unsigned int v4u __attribute__((ext_vector_type(4)));

static __device__ __forceinline__ unsigned short f2bf(float x) {
    unsigned u = __float_as_uint(x);
    return (unsigned short)((u + 0x7FFFu + ((u >> 16) & 1u)) >> 16);
}
static __device__ __forceinline__ float bf2f(unsigned short h) {
    return __uint_as_float((unsigned)h << 16);
}
static __device__ __forceinline__ unsigned f18(float p) {   // 1s+8e+9m, RN
    return ((__float_as_uint(p) + 0x2000u) >> 14) & 0x3FFFFu;
}

// ================= D1: HODLR moments (blocks 0..4095) + row hist (4096..6143)
__global__ __launch_bounds__(256) void kD1(const float* __restrict__ z,
                                           float2* __restrict__ M,
                                           float* __restrict__ S,
                                           float* __restrict__ out,
                                           const int* __restrict__ rows,
                                           unsigned* __restrict__ blockOff) {
    int b = blockIdx.x, t = threadIdx.x;
    if (b < 4096) {
        if (b == 0) {
            for (int i = t; i < 2046 * 2; i += 256) S[i] = 0.f;
            if (t == 0) out[0] = 0.f;
        }
        int lane = t & 63, wave = t >> 6;
        int chunk = b * 4 + wave;
        int base = chunk * 256 + lane * 4;
        float4 zv = *(const float4*)(z + base);
        float a0 = 0.f, a1 = 0.f;
        const float* zp = (const float*)&zv;
#pragma unroll
        for (int j = 0; j < 4; ++j) {
            float p = ((float)(base + j) + 0.5f) * (1.0f / 512.0f) - 0.5f;
            p = fminf(fmaxf(p, 0.0f), (float)(COARSE - 1));
            float f = p - floorf(p);
            a0 += zp[j] * (1.0f - f);
            a1 += zp[j] * f;
        }
#pragma unroll
        for (int off = 32; off >= 1; off >>= 1) {
            a0 += __shfl_xor(a0, off, 64);
            a1 += __shfl_xor(a1, off, 64);
        }
        if (lane == 0) M[chunk] = make_float2(a0, a1);
    } else {
        __shared__ unsigned h[NB];
        int blk = b - 4096;
        h[t] = 0u;
        __syncthreads();
        int base = blk * EPB;
#pragma unroll
        for (int it = 0; it < 4; ++it) {
            int e = base + it * 1024 + t * 4;
            v4i r = __builtin_nontemporal_load((const v4i*)(rows + e));
            atomicAdd(&h[r.x >> BSH], 1u); atomicAdd(&h[r.y >> BSH], 1u);
            atomicAdd(&h[r.z >> BSH], 1u); atomicAdd(&h[r.w >> BSH], 1u);
        }
        __syncthreads();
        blockOff[t * HB + blk] = h[t];
    }
}

// ================= D2: level sums (blocks 0..79) + per-bucket scan (80..335)
__global__ __launch_bounds__(256) void kD2(const float2* __restrict__ M,
                                           const float* __restrict__ V,
                                           float* __restrict__ S,
                                           unsigned* __restrict__ blockOff,
                                           unsigned* __restrict__ total) {
    int b = blockIdx.x, t = threadIdx.x;
    if (b < 80) {
        int lvl = b >> 3, slice = b & 7;
        const float2* Vl = (const float2*)(V + lvl * COARSE * 2);
        float s0 = 0.f, s1 = 0.f;
        int c0 = slice * 2048 + t * 8;
#pragma unroll
        for (int cc = 0; cc < 8; ++cc) {
            int c = c0 + cc;
            float2 m = M[c];
            int k = (c > 0) ? ((c - 1) >> 1) : 0;
            int kp = min(k + 1, COARSE - 1);
            float2 vk = Vl[k], vkp = Vl[kp];
            s0 += vk.x * m.x + vkp.x * m.y;
            s1 += vk.y * m.x + vkp.y * m.y;
        }
        int gw = min(1 << (10 - lvl), 64);   // threads per level-block group
        for (int sh = gw >> 1; sh >= 1; sh >>= 1) {
            s0 += __shfl_xor(s0, sh, 64);
            s1 += __shfl_xor(s1, sh, 64);
        }
        if ((t & (gw - 1)) == 0) {
            int bb = c0 >> (13 - lvl);
            int soff = (2 << lvl) - 2;
            unsafeAtomicAdd(&S[(soff + bb) * 2 + 0], s0);
            unsafeAtomicAdd(&S[(soff + bb) * 2 + 1], s1);
        }
    } else {
        int bb = b - 80;
        __shared__ unsigned wsum[4], wbase[4];
        unsigned* p = blockOff + bb * HB;
        v4u a = *(const v4u*)(p + t * 8);
        v4u c = *(const v4u*)(p + t * 8 + 4);
        unsigned s = a.x + a.y + a.z + a.w + c.x + c.y + c.z + c.w;
        unsigned incl = s;
#pragma unroll
        for (int off = 1; off < 64; off <<= 1) {
            unsigned n = __shfl_up(incl, off, 64);
            if ((t & 63) >= off) incl += n;
        }
        if ((t & 63) == 63) wsum[t >> 6] = incl;
        __syncthreads();
        if (t == 0) {
            unsigned acc = 0;
            for (int i = 0; i < 4; ++i) { wbase[i] = acc; acc += wsum[i]; }
            total[bb] = acc;
        }
        __syncthreads();
        unsigned excl = wbase[t >> 6] + incl - s;
        v4u e0, e1;
        e0.x = excl;       e0.y = e0.x + a.x; e0.z = e0.y + a.y; e0.w = e0.z + a.z;
        e1.x = e0.w + a.w; e1.y = e1.x + c.x; e1.z = e1.y + c.y; e1.w = e1.z + c.z;
        *(v4u*)(p + t * 8) = e0;
        *(v4u*)(p + t * 8 + 4) = e1;
    }
}

// ================= D3: fused per-chunk G + w = diag*z + lerp(G), bf16 out
__global__ __launch_bounds__(256) void kD3(const float* __restrict__ diag,
                                           const float* __restrict__ z,
                                           const float* __restrict__ S,
                                           const float* __restrict__ U,
                                           unsigned short* __restrict__ wb) {
    int tid = blockIdx.x * 256 + threadIdx.x;
    int base = tid * 4;
    int c = base >> 8;                    // chunk, wave-uniform
    int k = (c > 0) ? ((c - 1) >> 1) : 0;
    int kp = min(k + 1, COARSE - 1);
    float g0 = 0.f, g1 = 0.f;
#pragma unroll
    for (int lvl = 0; lvl < LEVELS; ++lvl) {
        int sib = (c >> (13 - lvl)) ^ 1;
        int soff = (2 << lvl) - 2;
        float2 s2 = ((const float2*)S)[soff + sib];
        const float2* Ul = (const float2*)(U + lvl * COARSE * 2);
        float2 uk = Ul[k], ukp = Ul[kp];
        g0 += uk.x * s2.x + uk.y * s2.y;
        g1 += ukp.x * s2.x + ukp.y * s2.y;
    }
    float4 d4 = *(const float4*)(diag + base);
    float4 z4 = *(const float4*)(z + base);
    const float* dp = (const float*)&d4;
    const float* zp = (const float*)&z4;
    ushort4 h4;
    unsigned short* hp = (unsigned short*)&h4;
#pragma unroll
    for (int j = 0; j < 4; ++j) {
        float p = ((float)(base + j) + 0.5f) * (1.0f / 512.0f) - 0.5f;
        p = fminf(fmaxf(p, 0.0f), (float)(COARSE - 1));
        float f = p - floorf(p);
        hp[j] = f2bf(dp[j] * zp[j] + (g0 + f * (g1 - g0)));
    }
    *(ushort4*)(wb + base) = h4;
}

// ================= D4: LDS-sorted binned scatter (coalesced global stores)
__global__ __launch_bounds__(256) void kD4(const int* __restrict__ rows,
                                           const int* __restrict__ cols,
                                           const float* __restrict__ vals,
                                           const unsigned short* __restrict__ wb,
                                           const unsigned* __restrict__ blockOff,
                                           const unsigned* __restrict__ total,
                                           unsigned* __restrict__ packed) {
    __shared__ unsigned cur[NB];          // hist -> scan -> running counters
    __shared__ unsigned gb[NB];           // global write base per bucket
    __shared__ unsigned wsum[4], wbase[4];
    __shared__ unsigned sortedP[EPB];     // 16 KiB packed entries, bucket-sorted
    __shared__ unsigned char sortedB[EPB];// 4 KiB bucket ids
    int blk = blockIdx.x, t = threadIdx.x;

    cur[t] = 0u;
    // bucket global bases: in-block exclusive scan of total[0..255]
    unsigned tv = total[t];
    unsigned incl = tv;
#pragma unroll
    for (int off = 1; off < 64; off <<= 1) {
        unsigned n = __shfl_up(incl, off, 64);
        if ((t & 63) >= off) incl += n;
    }
    if ((t & 63) == 63) wsum[t >> 6] = incl;
    __syncthreads();
    if (t == 0) {
        unsigned a = 0;
        for (int i = 0; i < 4; ++i) { wbase[i] = a; a += wsum[i]; }
    }
    __syncthreads();
    unsigned bucketBase = wbase[t >> 6] + incl - tv;

    // load 16 edges/thread, gather w
    int base = blk * EPB;
    v4i r[4], c[4];
    v4f v[4];
#pragma unroll
    for (int j = 0; j < 4; ++j) {
        int e = base + j * 1024 + t * 4;
        r[j] = __builtin_nontemporal_load((const v4i*)(rows + e));
        c[j] = __builtin_nontemporal_load((const v4i*)(cols + e));
        v[j] = __builtin_nontemporal_load((const v4f*)(vals + e));
    }
    unsigned short wv[16];
#pragma unroll
    for (int j = 0; j < 4; ++j) {
        const int* cp = (const int*)&c[j];
        wv[j * 4 + 0] = wb[cp[0]];
        wv[j * 4 + 1] = wb[cp[1]];
        wv[j * 4 + 2] = wb[cp[2]];
        wv[j * 4 + 3] = wb[cp[3]];
    }
    // local histogram
#pragma unroll
    for (int j = 0; j < 4; ++j) {
        const int* rp = (const int*)&r[j];
        atomicAdd(&cur[rp[0] >> BSH], 1u);
        atomicAdd(&cur[rp[1] >> BSH], 1u);
        atomicAdd(&cur[rp[2] >> BSH], 1u);
        atomicAdd(&cur[rp[3] >> BSH], 1u);
    }
    __syncthreads();
    // scan local hist -> lexcl; set gb and reset cur to lexcl
    unsigned lv = cur[t];
    unsigned lincl = lv;
#pragma unroll
    for (int off = 1; off < 64; off <<= 1) {
        unsigned n = __shfl_up(lincl, off, 64);
        if ((t & 63) >= off) lincl += n;
    }
    if ((t & 63) == 63) wsum[t >> 6] = lincl;
    __syncthreads();
    if (t == 0) {
        unsigned a = 0;
        for (int i = 0; i < 4; ++i) { wbase[i] = a; a += wsum[i]; }
    }
    __syncthreads();
    unsigned lexcl = wbase[t >> 6] + lincl - lv;
    gb[t] = bucketBase + blockOff[t * HB + blk] - lexcl;
    __syncthreads();   // ensure all reads of cur (lv) done before overwrite
    cur[t] = lexcl;
    __syncthreads();
    // placement into LDS, sorted by bucket
#pragma unroll
    for (int j = 0; j < 4; ++j) {
        const int* rp = (const int*)&r[j];
        const float* vp = (const float*)&v[j];
#pragma unroll
        for (int kk = 0; kk < 4; ++kk) {
            int row = rp[kk];
            unsigned bkt = (unsigned)row >> BSH;
            float p = vp[kk] * bf2f(wv[j * 4 + kk]);
            unsigned i = atomicAdd(&cur[bkt], 1u);
            sortedP[i] = ((unsigned)(row & (BROWS - 1)) << 18) | f18(p);
            sortedB[i] = (unsigned char)bkt;
        }
    }
    __syncthreads();
    // coalesced write-out: consecutive i -> consecutive global addresses per bucket
#pragma unroll
    for (int k = 0; k < 16; ++k) {
        int i = k * 256 + t;
        unsigned bkt = sortedB[i];
        __builtin_nontemporal_store(sortedP[i], packed + gb[bkt] + i);
    }
}

// ================= D5: per row-bucket LDS accumulate + fused loss
__global__ __launch_bounds__(1024) void kD5(const unsigned* __restrict__ packed,
                                            const unsigned* __restrict__ total,
                                            const float* __restrict__ z,
                                            float* __restrict__ out) {
    __shared__ float acc[BROWS];          // 64 KiB
    __shared__ unsigned sb, sn;
    __shared__ unsigned wsum[4], wbase[4];
    __shared__ float red[16];
    int b = blockIdx.x, t = threadIdx.x;

    unsigned tv = 0, incl = 0;
    if (t < 256) {
        tv = total[t];
        incl = tv;
#pragma unroll
        for (int off = 1; off < 64; off <<= 1) {
            unsigned n = __shfl_up(incl, off, 64);
            if ((t & 63) >= off) incl += n;
        }
        if ((t & 63) == 63) wsum[t >> 6] = incl;
    }
    __syncthreads();
    if (t == 0) {
        unsigned a = 0;
        for (int i = 0; i < 4; ++i) { wbase[i] = a; a += wsum[i]; }
    }
    __syncthreads();
    if (t < 256 && t == b) { sb = wbase[t >> 6] + incl - tv; sn = tv; }
    for (int i = t; i < BROWS / 4; i += 1024) ((float4*)acc)[i] = make_float4(0.f, 0.f, 0.f, 0.f);
    __syncthreads();

    unsigned s0 = sb, n = sn;
    for (unsigned i = t; i < n; i += 1024) {
        unsigned e = __builtin_nontemporal_load(packed + s0 + i);
        atomicAdd(&acc[e >> 18], __uint_as_float((e & 0x3FFFFu) << 14));
    }
    __syncthreads();

    float part = 0.f;
    int gbase = b * BROWS;
    for (int i = t; i < BROWS; i += 1024) {
        float d = acc[i] - z[gbase + i];
        part += d * d;
    }
#pragma unroll
    for (int off = 32; off >= 1; off >>= 1) part += __shfl_xor(part, off, 64);
    if ((t & 63) == 0) red[t >> 6] = part;
    __syncthreads();
    if (t == 0) {
        float s = 0.f;
        for (int i = 0; i < 16; ++i) s += red[i];
        unsafeAtomicAdd(out, s * (1.0f / (float)N_NODES));
    }
}

extern "C" void kernel_launch(void* const* d_in, const int* in_sizes, int n_in,
                              void* d_out, int out_size, void* d_ws, size_t ws_size,
                              hipStream_t stream) {
    const float* diag  = (const float*)d_in[0];
    const float* U     = (const float*)d_in[1];
    const float* V     = (const float*)d_in[2];
    const float* Avals = (const float*)d_in[3];
    const float* z     = (const float*)d_in[4];
    const int*   Aidx  = (const int*)d_in[5];
    const int* rows = Aidx;
    const int* cols = Aidx + NNZ_E;

    char* ws = (char*)d_ws;
    size_t off = 0;
    unsigned short* wb = (unsigned short*)(ws + off); off += (size_t)N_NODES * 2;  // 8 MiB
    unsigned* packed   = (unsigned*)(ws + off);       off += (size_t)NNZ_E * 4;    // 32 MiB
    unsigned* blockOff = (unsigned*)(ws + off);       off += (size_t)NB * HB * 4;  // 2 MiB
    unsigned* total    = (unsigned*)(ws + off);       off += 1024;
    float2* M          = (float2*)(ws + off);         off += (size_t)NCHUNK * 8;   // 128 KiB
    float* S           = (float*)(ws + off);          off += 16384;

    kD1<<<6144, 256, 0, stream>>>(z, M, S, (float*)d_out, rows, blockOff);
    kD2<<<336, 256, 0, stream>>>(M, V, S, blockOff, total);
    kD3<<<4096, 256, 0, stream>>>(diag, z, S, U, wb);
    kD4<<<HB, 256, 0, stream>>>(rows, cols, Avals, wb, blockOff, total, packed);
    kD5<<<NB, 1024, 0, stream>>>(packed, total, z, (float*)d_out);
}

// Round 8
// 311.801 us; speedup vs baseline: 1.1447x; 1.0520x over previous
//
#include <hip/hip_runtime.h>

#define N_NODES 4194304
#define LEVELS  10
#define COARSE  8192
#define NNZ_E   8388608
#define NCHUNK  16384    // N_NODES / 256
#define NB      256      // row buckets == col buckets
#define CB_SZ   16384    // cols per col-bucket (32 KiB bf16 LDS slice)
#define RB_SZ   16384    // rows per row-bucket (64 KiB LDS accumulator)
#define HB      1024     // hist/binning blocks
#define EPB     8192     // edges per binning block
#define TILE    8192     // kD tile size

typedef int          v4i __attribute__((ext_vector_type(4)));
typedef float        v4f __attribute__((ext_vector_type(4)));
typedef unsigned int v4u __attribute__((ext_vector_type(4)));
typedef unsigned int v2u __attribute__((ext_vector_type(2)));

static __device__ __forceinline__ unsigned short f2bf(float x) {
    unsigned u = __float_as_uint(x);
    return (unsigned short)((u + 0x7FFFu + ((u >> 16) & 1u)) >> 16);
}
static __device__ __forceinline__ float bf2f(unsigned short h) {
    return __uint_as_float((unsigned)h << 16);
}
static __device__ __forceinline__ unsigned f18(float p) {   // 1s+8e+9m, RN
    return ((__float_as_uint(p) + 0x2000u) >> 14) & 0x3FFFFu;
}

// ============ kA: HODLR moments (blocks 0..2047) + dual row/col hist (2048..3071)
__global__ __launch_bounds__(512) void kA(const float* __restrict__ z,
                                          float2* __restrict__ M,
                                          float* __restrict__ S,
                                          float* __restrict__ out,
                                          const int* __restrict__ rows,
                                          const int* __restrict__ cols,
                                          unsigned* __restrict__ colBO,
                                          unsigned* __restrict__ rowBC) {
    int b = blockIdx.x, t = threadIdx.x;
    if (b < 2048) {
        if (b == 0) {
            for (int i = t; i < 2046 * 2; i += 512) S[i] = 0.f;
            if (t == 0) out[0] = 0.f;
        }
        int lane = t & 63, wave = t >> 6;
        int chunk = b * 8 + wave;
        int base = chunk * 256 + lane * 4;
        float4 zv = *(const float4*)(z + base);
        float a0 = 0.f, a1 = 0.f;
        const float* zp = (const float*)&zv;
#pragma unroll
        for (int j = 0; j < 4; ++j) {
            float p = ((float)(base + j) + 0.5f) * (1.0f / 512.0f) - 0.5f;
            p = fminf(fmaxf(p, 0.0f), (float)(COARSE - 1));
            float f = p - floorf(p);
            a0 += zp[j] * (1.0f - f);
            a1 += zp[j] * f;
        }
#pragma unroll
        for (int off = 32; off >= 1; off >>= 1) {
            a0 += __shfl_xor(a0, off, 64);
            a1 += __shfl_xor(a1, off, 64);
        }
        if (lane == 0) M[chunk] = make_float2(a0, a1);
    } else {
        __shared__ unsigned hc[NB], hr[NB];
        int blk = b - 2048;
        if (t < 256) { hc[t] = 0u; hr[t] = 0u; }
        __syncthreads();
        int base = blk * EPB;
#pragma unroll
        for (int it = 0; it < 4; ++it) {
            int e = base + it * 2048 + t * 4;
            v4i r = __builtin_nontemporal_load((const v4i*)(rows + e));
            v4i c = __builtin_nontemporal_load((const v4i*)(cols + e));
            atomicAdd(&hr[r.x >> 14], 1u); atomicAdd(&hr[r.y >> 14], 1u);
            atomicAdd(&hr[r.z >> 14], 1u); atomicAdd(&hr[r.w >> 14], 1u);
            atomicAdd(&hc[c.x >> 14], 1u); atomicAdd(&hc[c.y >> 14], 1u);
            atomicAdd(&hc[c.z >> 14], 1u); atomicAdd(&hc[c.w >> 14], 1u);
        }
        __syncthreads();
        if (t < 256) {
            colBO[t * HB + blk] = hc[t];
            rowBC[t * HB + blk] = hr[t];
        }
    }
}

// ============ kB: level sums (0..79) + col per-bucket scan (80..335) + row totals (336..591)
__global__ __launch_bounds__(256) void kB(const float2* __restrict__ M,
                                          const float* __restrict__ V,
                                          float* __restrict__ S,
                                          unsigned* __restrict__ colBO,
                                          unsigned* __restrict__ colTotal,
                                          const unsigned* __restrict__ rowBC,
                                          unsigned* __restrict__ rowTotal) {
    int b = blockIdx.x, t = threadIdx.x;
    if (b < 80) {
        int lvl = b >> 3, slice = b & 7;
        const float2* Vl = (const float2*)(V + lvl * COARSE * 2);
        float s0 = 0.f, s1 = 0.f;
        int c0 = slice * 2048 + t * 8;
#pragma unroll
        for (int cc = 0; cc < 8; ++cc) {
            int c = c0 + cc;
            float2 m = M[c];
            int k = (c > 0) ? ((c - 1) >> 1) : 0;
            int kp = min(k + 1, COARSE - 1);
            float2 vk = Vl[k], vkp = Vl[kp];
            s0 += vk.x * m.x + vkp.x * m.y;
            s1 += vk.y * m.x + vkp.y * m.y;
        }
        int gw = min(1 << (10 - lvl), 64);
        for (int sh = gw >> 1; sh >= 1; sh >>= 1) {
            s0 += __shfl_xor(s0, sh, 64);
            s1 += __shfl_xor(s1, sh, 64);
        }
        if ((t & (gw - 1)) == 0) {
            int bb = c0 >> (13 - lvl);
            int soff = (2 << lvl) - 2;
            unsafeAtomicAdd(&S[(soff + bb) * 2 + 0], s0);
            unsafeAtomicAdd(&S[(soff + bb) * 2 + 1], s1);
        }
    } else if (b < 336) {
        int bb = b - 80;
        __shared__ unsigned wsum[4], wbase[4];
        unsigned* p = colBO + bb * HB;
        v4u a = ((const v4u*)p)[t];
        unsigned s = a.x + a.y + a.z + a.w;
        unsigned incl = s;
#pragma unroll
        for (int off = 1; off < 64; off <<= 1) {
            unsigned n = __shfl_up(incl, off, 64);
            if ((t & 63) >= off) incl += n;
        }
        if ((t & 63) == 63) wsum[t >> 6] = incl;
        __syncthreads();
        if (t == 0) {
            unsigned acc = 0;
            for (int i = 0; i < 4; ++i) { wbase[i] = acc; acc += wsum[i]; }
            colTotal[bb] = acc;
        }
        __syncthreads();
        unsigned excl = wbase[t >> 6] + incl - s;
        v4u e;
        e.x = excl; e.y = excl + a.x; e.z = e.y + a.y; e.w = e.z + a.z;
        ((v4u*)p)[t] = e;
    } else {
        int bb = b - 336;
        __shared__ unsigned red[4];
        v4u vv = ((const v4u*)(rowBC + bb * HB))[t];
        unsigned s = vv.x + vv.y + vv.z + vv.w;
#pragma unroll
        for (int off = 32; off >= 1; off >>= 1) s += __shfl_xor(s, off, 64);
        if ((t & 63) == 0) red[t >> 6] = s;
        __syncthreads();
        if (t == 0) rowTotal[bb] = red[0] + red[1] + red[2] + red[3];
    }
}

// ============ kC: w=diag*z+lowrank->bf16 (0..2047) + col-binning (2048..3071) + rowCtr init (3072)
__global__ __launch_bounds__(512) void kC(const float* __restrict__ diag,
                                          const float* __restrict__ z,
                                          const float* __restrict__ S,
                                          const float* __restrict__ U,
                                          unsigned short* __restrict__ wb,
                                          const int* __restrict__ rows,
                                          const int* __restrict__ cols,
                                          const float* __restrict__ vals,
                                          const unsigned* __restrict__ colBO,
                                          const unsigned* __restrict__ colTotal,
                                          v2u* __restrict__ colBinned,
                                          const unsigned* __restrict__ rowTotal,
                                          unsigned* __restrict__ rowCtr) {
    int b = blockIdx.x, t = threadIdx.x;
    if (b < 2048) {
        int tid = b * 512 + t;
        int base = tid * 4;
        int c = base >> 8;                // wave-uniform chunk
        int k = (c > 0) ? ((c - 1) >> 1) : 0;
        int kp = min(k + 1, COARSE - 1);
        float g0 = 0.f, g1 = 0.f;
#pragma unroll
        for (int lvl = 0; lvl < LEVELS; ++lvl) {
            int sib = (c >> (13 - lvl)) ^ 1;
            int soff = (2 << lvl) - 2;
            float2 s2 = ((const float2*)S)[soff + sib];
            const float2* Ul = (const float2*)(U + lvl * COARSE * 2);
            float2 uk = Ul[k], ukp = Ul[kp];
            g0 += uk.x * s2.x + uk.y * s2.y;
            g1 += ukp.x * s2.x + ukp.y * s2.y;
        }
        float4 d4 = *(const float4*)(diag + base);
        float4 z4 = *(const float4*)(z + base);
        const float* dp = (const float*)&d4;
        const float* zp = (const float*)&z4;
        ushort4 h4;
        unsigned short* hp = (unsigned short*)&h4;
#pragma unroll
        for (int j = 0; j < 4; ++j) {
            float p = ((float)(base + j) + 0.5f) * (1.0f / 512.0f) - 0.5f;
            p = fminf(fmaxf(p, 0.0f), (float)(COARSE - 1));
            float f = p - floorf(p);
            hp[j] = f2bf(dp[j] * zp[j] + (g0 + f * (g1 - g0)));
        }
        *(ushort4*)(wb + base) = h4;
    } else if (b < 3072) {
        __shared__ v2u sortedP[EPB];           // 64 KiB
        __shared__ unsigned char sortedB[EPB]; // 8 KiB
        __shared__ unsigned cur[NB], gb[NB];
        __shared__ unsigned wsum[4], wbase[4];
        int blk = b - 2048;
        int base = blk * EPB;
        // start streaming loads early
        v4i r[4], c[4];
        v4f v[4];
#pragma unroll
        for (int j = 0; j < 4; ++j) {
            int e = base + j * 2048 + t * 4;
            r[j] = __builtin_nontemporal_load((const v4i*)(rows + e));
            c[j] = __builtin_nontemporal_load((const v4i*)(cols + e));
            v[j] = __builtin_nontemporal_load((const v4f*)(vals + e));
        }
        // global segment base per col bucket: scan colTotal
        unsigned tv = (t < 256) ? colTotal[t] : 0u;
        unsigned incl = tv;
        if (t < 256) {
#pragma unroll
            for (int off = 1; off < 64; off <<= 1) {
                unsigned n = __shfl_up(incl, off, 64);
                if ((t & 63) >= off) incl += n;
            }
            if ((t & 63) == 63) wsum[t >> 6] = incl;
            cur[t] = 0u;
        }
        __syncthreads();
        if (t == 0) {
            unsigned a = 0;
            for (int i = 0; i < 4; ++i) { wbase[i] = a; a += wsum[i]; }
        }
        __syncthreads();
        unsigned segBase = (t < 256) ? (wbase[t >> 6] + incl - tv) : 0u;
        // local histogram by col bucket
#pragma unroll
        for (int j = 0; j < 4; ++j) {
            atomicAdd(&cur[c[j].x >> 14], 1u);
            atomicAdd(&cur[c[j].y >> 14], 1u);
            atomicAdd(&cur[c[j].z >> 14], 1u);
            atomicAdd(&cur[c[j].w >> 14], 1u);
        }
        __syncthreads();
        // scan local hist
        unsigned lv = (t < 256) ? cur[t] : 0u;
        unsigned lincl = lv;
        if (t < 256) {
#pragma unroll
            for (int off = 1; off < 64; off <<= 1) {
                unsigned n = __shfl_up(lincl, off, 64);
                if ((t & 63) >= off) lincl += n;
            }
            if ((t & 63) == 63) wsum[t >> 6] = lincl;
        }
        __syncthreads();
        if (t == 0) {
            unsigned a = 0;
            for (int i = 0; i < 4; ++i) { wbase[i] = a; a += wsum[i]; }
        }
        __syncthreads();
        if (t < 256) {
            unsigned lexcl = wbase[t >> 6] + lincl - lv;
            gb[t] = segBase + colBO[t * HB + blk] - lexcl;
            cur[t] = lexcl;
        }
        __syncthreads();
        // place, sorted by col bucket
#pragma unroll
        for (int j = 0; j < 4; ++j) {
            const int* rp = (const int*)&r[j];
            const int* cp = (const int*)&c[j];
            const float* vp = (const float*)&v[j];
#pragma unroll
            for (int kk = 0; kk < 4; ++kk) {
                int row = rp[kk], col = cp[kk];
                unsigned cb = (unsigned)col >> 14;
                unsigned cl = (unsigned)col & 16383u;
                v2u ent;
                ent.x = (unsigned)row | ((cl & 0x3FFu) << 22);
                ent.y = (cl >> 10) | ((unsigned)f2bf(vp[kk]) << 16);
                unsigned i = atomicAdd(&cur[cb], 1u);
                sortedP[i] = ent;
                sortedB[i] = (unsigned char)cb;
            }
        }
        __syncthreads();
        // coalesced write-out
#pragma unroll
        for (int k = 0; k < 16; ++k) {
            int i = k * 512 + t;
            unsigned bkt = sortedB[i];
            __builtin_nontemporal_store(sortedP[i], colBinned + gb[bkt] + i);
        }
    } else {
        // rowCtr init: exclusive scan of rowTotal
        __shared__ unsigned wsum[4], wbase[4];
        unsigned tv = (t < 256) ? rowTotal[t] : 0u;
        unsigned incl = tv;
        if (t < 256) {
#pragma unroll
            for (int off = 1; off < 64; off <<= 1) {
                unsigned n = __shfl_up(incl, off, 64);
                if ((t & 63) >= off) incl += n;
            }
            if ((t & 63) == 63) wsum[t >> 6] = incl;
        }
        __syncthreads();
        if (t == 0) {
            unsigned a = 0;
            for (int i = 0; i < 4; ++i) { wbase[i] = a; a += wsum[i]; }
        }
        __syncthreads();
        if (t < 256) rowCtr[t] = wbase[t >> 6] + incl - tv;
    }
}

// ============ kD: per col-bucket — products via LDS w-slice, LDS-sorted row-bucket scatter
__global__ __launch_bounds__(512) void kD(const unsigned short* __restrict__ wb,
                                          const v2u* __restrict__ colBinned,
                                          const unsigned* __restrict__ colTotal,
                                          unsigned* __restrict__ rowCtr,
                                          unsigned* __restrict__ packed) {
    __shared__ unsigned short wSl[CB_SZ];   // 32 KiB
    __shared__ unsigned sortedP[TILE];      // 32 KiB
    __shared__ unsigned char sortedB[TILE]; // 8 KiB
    __shared__ unsigned cur[NB], gb[NB];
    __shared__ unsigned wsum[4], wbase[4];
    __shared__ unsigned sS;
    int b = blockIdx.x, t = threadIdx.x;

    // segment base: scan colTotal
    unsigned tv = (t < 256) ? colTotal[t] : 0u;
    unsigned incl = tv;
    if (t < 256) {
#pragma unroll
        for (int off = 1; off < 64; off <<= 1) {
            unsigned n = __shfl_up(incl, off, 64);
            if ((t & 63) >= off) incl += n;
        }
        if ((t & 63) == 63) wsum[t >> 6] = incl;
    }
    __syncthreads();
    if (t == 0) {
        unsigned a = 0;
        for (int i = 0; i < 4; ++i) { wbase[i] = a; a += wsum[i]; }
    }
    __syncthreads();
    if (t < 256 && t == b) sS = wbase[t >> 6] + incl - tv;
    // load w slice (bf16) into LDS
    const v4u* wg = (const v4u*)(wb + (size_t)b * CB_SZ);
    for (int i = t; i < CB_SZ / 8; i += 512) ((v4u*)wSl)[i] = wg[i];
    __syncthreads();
    unsigned s0 = sS, n = colTotal[b];

    for (unsigned t0 = 0; t0 < n; t0 += TILE) {
        unsigned cnt = min((unsigned)TILE, n - t0);
        if (t < 256) cur[t] = 0u;
        __syncthreads();
        v2u ev[16];
#pragma unroll
        for (int k = 0; k < 16; ++k) {
            unsigned i = (unsigned)(k * 512 + t);
            if (i < cnt) ev[k] = __builtin_nontemporal_load(colBinned + s0 + t0 + i);
        }
#pragma unroll
        for (int k = 0; k < 16; ++k) {
            if ((unsigned)(k * 512 + t) < cnt)
                atomicAdd(&cur[(ev[k].x & 0x3FFFFFu) >> 14], 1u);
        }
        __syncthreads();
        unsigned lv = (t < 256) ? cur[t] : 0u;
        unsigned lincl = lv;
        if (t < 256) {
#pragma unroll
            for (int off = 1; off < 64; off <<= 1) {
                unsigned nn = __shfl_up(lincl, off, 64);
                if ((t & 63) >= off) lincl += nn;
            }
            if ((t & 63) == 63) wsum[t >> 6] = lincl;
        }
        __syncthreads();
        if (t == 0) {
            unsigned a = 0;
            for (int i = 0; i < 4; ++i) { wbase[i] = a; a += wsum[i]; }
        }
        __syncthreads();
        if (t < 256) {
            unsigned lexcl = wbase[t >> 6] + lincl - lv;
            gb[t] = atomicAdd(&rowCtr[t], lv) - lexcl;
            cur[t] = lexcl;
        }
        __syncthreads();
#pragma unroll
        for (int k = 0; k < 16; ++k) {
            if ((unsigned)(k * 512 + t) < cnt) {
                v2u e = ev[k];
                unsigned row = e.x & 0x3FFFFFu;
                unsigned cl = (e.x >> 22) | ((e.y & 0xFu) << 10);
                float p = bf2f((unsigned short)(e.y >> 16)) * bf2f(wSl[cl]);
                unsigned rb = row >> 14;
                unsigned i = atomicAdd(&cur[rb], 1u);
                sortedP[i] = ((row & 16383u) << 18) | f18(p);
                sortedB[i] = (unsigned char)rb;
            }
        }
        __syncthreads();
#pragma unroll
        for (int k = 0; k < 16; ++k) {
            unsigned i = (unsigned)(k * 512 + t);
            if (i < cnt) {
                unsigned bkt = sortedB[i];
                __builtin_nontemporal_store(sortedP[i], packed + gb[bkt] + i);
            }
        }
        __syncthreads();
    }
}

// ============ kE: per row-bucket LDS accumulate + fused loss
__global__ __launch_bounds__(1024) void kE(const unsigned* __restrict__ packed,
                                           const unsigned* __restrict__ rowTotal,
                                           const float* __restrict__ z,
                                           float* __restrict__ out) {
    __shared__ float acc[RB_SZ];          // 64 KiB
    __shared__ unsigned sb;
    __shared__ unsigned wsum[4], wbase[4];
    __shared__ float red[16];
    int b = blockIdx.x, t = threadIdx.x;

    unsigned tv = (t < 256) ? rowTotal[t] : 0u;
    unsigned incl = tv;
    if (t < 256) {
#pragma unroll
        for (int off = 1; off < 64; off <<= 1) {
            unsigned n = __shfl_up(incl, off, 64);
            if ((t & 63) >= off) incl += n;
        }
        if ((t & 63) == 63) wsum[t >> 6] = incl;
    }
    __syncthreads();
    if (t == 0) {
        unsigned a = 0;
        for (int i = 0; i < 4; ++i) { wbase[i] = a; a += wsum[i]; }
    }
    __syncthreads();
    if (t < 256 && t == b) sb = wbase[t >> 6] + incl - tv;
    for (int i = t; i < RB_SZ / 4; i += 1024) ((float4*)acc)[i] = make_float4(0.f, 0.f, 0.f, 0.f);
    __syncthreads();

    unsigned s0 = sb, n = rowTotal[b];
    for (unsigned i = t; i < n; i += 1024) {
        unsigned e = __builtin_nontemporal_load(packed + s0 + i);
        atomicAdd(&acc[e >> 18], __uint_as_float((e & 0x3FFFFu) << 14));
    }
    __syncthreads();

    float part = 0.f;
    int gbase = b * RB_SZ;
    for (int i = t; i < RB_SZ; i += 1024) {
        float d = acc[i] - z[gbase + i];
        part += d * d;
    }
#pragma unroll
    for (int off = 32; off >= 1; off >>= 1) part += __shfl_xor(part, off, 64);
    if ((t & 63) == 0) red[t >> 6] = part;
    __syncthreads();
    if (t == 0) {
        float s = 0.f;
        for (int i = 0; i < 16; ++i) s += red[i];
        unsafeAtomicAdd(out, s * (1.0f / (float)N_NODES));
    }
}

extern "C" void kernel_launch(void* const* d_in, const int* in_sizes, int n_in,
                              void* d_out, int out_size, void* d_ws, size_t ws_size,
                              hipStream_t stream) {
    const float* diag  = (const float*)d_in[0];
    const float* U     = (const float*)d_in[1];
    const float* V     = (const float*)d_in[2];
    const float* Avals = (const float*)d_in[3];
    const float* z     = (const float*)d_in[4];
    const int*   Aidx  = (const int*)d_in[5];
    const int* rows = Aidx;
    const int* cols = Aidx + NNZ_E;

    char* ws = (char*)d_ws;
    size_t off = 0;
    unsigned short* wb  = (unsigned short*)(ws + off); off += (size_t)N_NODES * 2;  // 8 MiB
    v2u* colBinned      = (v2u*)(ws + off);            off += (size_t)NNZ_E * 8;    // 64 MiB
    unsigned* packed    = (unsigned*)(ws + off);       off += (size_t)NNZ_E * 4;    // 32 MiB
    unsigned* colBO     = (unsigned*)(ws + off);       off += (size_t)NB * HB * 4;  // 1 MiB
    unsigned* rowBC     = (unsigned*)(ws + off);       off += (size_t)NB * HB * 4;  // 1 MiB
    unsigned* colTotal  = (unsigned*)(ws + off);       off += 1024;
    unsigned* rowTotal  = (unsigned*)(ws + off);       off += 1024;
    unsigned* rowCtr    = (unsigned*)(ws + off);       off += 1024;
    float2* M           = (float2*)(ws + off);         off += (size_t)NCHUNK * 8;   // 128 KiB
    float* S            = (float*)(ws + off);          off += 16384;

    kA<<<3072, 512, 0, stream>>>(z, M, S, (float*)d_out, rows, cols, colBO, rowBC);
    kB<<<592, 256, 0, stream>>>(M, V, S, colBO, colTotal, rowBC, rowTotal);
    kC<<<3073, 512, 0, stream>>>(diag, z, S, U, wb, rows, cols, Avals,
                                 colBO, colTotal, colBinned, rowTotal, rowCtr);
    kD<<<NB, 512, 0, stream>>>(wb, colBinned, colTotal, rowCtr, packed);
    kE<<<NB, 1024, 0, stream>>>(packed, rowTotal, z, (float*)d_out);
}